// Round 3
// baseline (89.925 us; speedup 1.0000x reference)
//
#include <hip/hip_runtime.h>

// ClusterLoss: loss = 0.5 * sum_{b,d} (X[b,d] - C[id[b],d])^2
// B=65536, D=1024, K=256.
// Memory-bound: one streaming pass over X (256 MiB); C (1 MiB) is L2-resident.
// X loaded nontemporally (evict-first) so the stream doesn't displace C in L2.
// ids hoisted to SGPRs once per block; 8 rows of X in flight per batch.

typedef float f4 __attribute__((ext_vector_type(4)));

#define D_DIM 1024
#define BLOCK 256          // thread t covers float4 at column t*4 -> one row per row-step
#define ROWS_PER_BLOCK 32  // 65536 / 2048 blocks
#define CHUNK 8            // X rows in flight per batch

__global__ __launch_bounds__(BLOCK, 8) void cluster_loss_kernel(
    const float* __restrict__ X,
    const int*   __restrict__ ids,
    const float* __restrict__ C,
    float*       __restrict__ out,
    int B)
{
    const int t = threadIdx.x;
    const int row0 = blockIdx.x * ROWS_PER_BLOCK;
    float acc = 0.0f;

    if (row0 + ROWS_PER_BLOCK <= B) {
        // Hoist all ids for this block: uniform -> one s_load burst, the
        // id->C dependent chain is paid once per block, not per batch.
        int id[ROWS_PER_BLOCK];
        #pragma unroll
        for (int i = 0; i < ROWS_PER_BLOCK; ++i) id[i] = ids[row0 + i];

        const float* xb = X + (size_t)row0 * D_DIM + t * 4;
        const float* cb = C + t * 4;

        #pragma unroll 1
        for (int i = 0; i < ROWS_PER_BLOCK; i += CHUNK) {
            f4 x[CHUNK];
            // batch-issue 8 streaming X loads (128 B/lane in flight)
            #pragma unroll
            for (int u = 0; u < CHUNK; ++u)
                x[u] = __builtin_nontemporal_load(
                         reinterpret_cast<const f4*>(xb + (size_t)(i + u) * D_DIM));
            // consume with C gathers in two sub-batches of 4 (keeps VGPRs < 64)
            #pragma unroll
            for (int h = 0; h < 2; ++h) {
                f4 c[4];
                #pragma unroll
                for (int v = 0; v < 4; ++v)
                    c[v] = *reinterpret_cast<const f4*>(
                             cb + (size_t)id[i + h * 4 + v] * D_DIM);
                #pragma unroll
                for (int v = 0; v < 4; ++v) {
                    const f4 d = x[h * 4 + v] - c[v];
                    acc = fmaf(d.x, d.x, acc);
                    acc = fmaf(d.y, d.y, acc);
                    acc = fmaf(d.z, d.z, acc);
                    acc = fmaf(d.w, d.w, acc);
                }
            }
        }
    } else {
        for (int row = row0; row < B; ++row) {
            const int id = ids[row];
            const f4 x = __builtin_nontemporal_load(
                           reinterpret_cast<const f4*>(X + (size_t)row * D_DIM + t * 4));
            const f4 c = *reinterpret_cast<const f4*>(C + (size_t)id * D_DIM + t * 4);
            const f4 d = x - c;
            acc = fmaf(d.x, d.x, acc);
            acc = fmaf(d.y, d.y, acc);
            acc = fmaf(d.z, d.z, acc);
            acc = fmaf(d.w, d.w, acc);
        }
    }

    // wave-64 butterfly reduce
    #pragma unroll
    for (int off = 32; off > 0; off >>= 1)
        acc += __shfl_down(acc, off, 64);

    __shared__ float wave_sum[BLOCK / 64];
    if ((t & 63) == 0) wave_sum[t >> 6] = acc;
    __syncthreads();

    if (t == 0) {
        float s = wave_sum[0] + wave_sum[1] + wave_sum[2] + wave_sum[3];
        atomicAdd(out, 0.5f * s);
    }
}

extern "C" void kernel_launch(void* const* d_in, const int* in_sizes, int n_in,
                              void* d_out, int out_size, void* d_ws, size_t ws_size,
                              hipStream_t stream)
{
    const float* X   = (const float*)d_in[0];
    const int*   ids = (const int*)  d_in[1];
    const float* C   = (const float*)d_in[2];
    float*       out = (float*)d_out;

    const int B = in_sizes[1];  // 65536 rows

    // d_out is poisoned (0xAA) before timing and not re-zeroed between replays.
    hipMemsetAsync(out, 0, sizeof(float), stream);

    const int grid = (B + ROWS_PER_BLOCK - 1) / ROWS_PER_BLOCK;  // 2048
    cluster_loss_kernel<<<grid, BLOCK, 0, stream>>>(X, ids, C, out, B);
}

// Round 4
// 60.499 us; speedup vs baseline: 1.4864x; 1.4864x over previous
//
#include <hip/hip_runtime.h>

// ClusterLoss: loss = 0.5 * sum_{b,d} (X[b,d] - C[id[b],d])^2
// B=65536, D=1024, K=256.
// Memory-bound: one streaming pass over X (256 MiB); C (1 MiB) is L2-resident.
// X loaded nontemporally (evict-first) so the stream doesn't displace C in L2.
// 1-deep software pipeline: batch i+1's X loads issued before batch i's
// C-gather + FMA consume, so the HBM round-trip overlaps the consume phase.

typedef float f4 __attribute__((ext_vector_type(4)));

#define D_DIM 1024
#define BLOCK 256          // thread t covers float4 at column t*4 -> one row per row-step
#define ROWS_PER_BLOCK 32  // 65536 / 2048 blocks
#define CHUNK 4            // rows per pipeline stage

__global__ void cluster_loss_kernel(
    const float* __restrict__ X,
    const int*   __restrict__ ids,
    const float* __restrict__ C,
    float*       __restrict__ out,
    int B)
{
    const int t = threadIdx.x;
    const int row0 = blockIdx.x * ROWS_PER_BLOCK;
    float acc = 0.0f;

    if (row0 + ROWS_PER_BLOCK <= B) {
        const float* xb = X + (size_t)row0 * D_DIM + t * 4;
        const float* cb = C + t * 4;

        // prologue: issue batch 0
        int id[CHUNK];
        f4  x[CHUNK];
        #pragma unroll
        for (int u = 0; u < CHUNK; ++u) {
            id[u] = ids[row0 + u];               // block-uniform -> scalar load
            x[u]  = __builtin_nontemporal_load(
                      reinterpret_cast<const f4*>(xb + (size_t)u * D_DIM));
        }

        #pragma unroll 1
        for (int i = 0; i < ROWS_PER_BLOCK - CHUNK; i += CHUNK) {
            // issue batch i+1 (X stream + ids) before consuming batch i
            int idn[CHUNK];
            f4  xn[CHUNK];
            #pragma unroll
            for (int u = 0; u < CHUNK; ++u) {
                idn[u] = ids[row0 + i + CHUNK + u];
                xn[u]  = __builtin_nontemporal_load(
                           reinterpret_cast<const f4*>(xb + (size_t)(i + CHUNK + u) * D_DIM));
            }
            // consume batch i: C gather (L2-resident) + FMA
            #pragma unroll
            for (int u = 0; u < CHUNK; ++u) {
                const f4 c = *reinterpret_cast<const f4*>(cb + (size_t)id[u] * D_DIM);
                const f4 d = x[u] - c;
                acc = fmaf(d.x, d.x, acc);
                acc = fmaf(d.y, d.y, acc);
                acc = fmaf(d.z, d.z, acc);
                acc = fmaf(d.w, d.w, acc);
            }
            // rotate
            #pragma unroll
            for (int u = 0; u < CHUNK; ++u) { id[u] = idn[u]; x[u] = xn[u]; }
        }

        // epilogue: consume the final batch
        #pragma unroll
        for (int u = 0; u < CHUNK; ++u) {
            const f4 c = *reinterpret_cast<const f4*>(cb + (size_t)id[u] * D_DIM);
            const f4 d = x[u] - c;
            acc = fmaf(d.x, d.x, acc);
            acc = fmaf(d.y, d.y, acc);
            acc = fmaf(d.z, d.z, acc);
            acc = fmaf(d.w, d.w, acc);
        }
    } else {
        for (int row = row0; row < B; ++row) {
            const int id = ids[row];
            const f4 x = __builtin_nontemporal_load(
                           reinterpret_cast<const f4*>(X + (size_t)row * D_DIM + t * 4));
            const f4 c = *reinterpret_cast<const f4*>(C + (size_t)id * D_DIM + t * 4);
            const f4 d = x - c;
            acc = fmaf(d.x, d.x, acc);
            acc = fmaf(d.y, d.y, acc);
            acc = fmaf(d.z, d.z, acc);
            acc = fmaf(d.w, d.w, acc);
        }
    }

    // wave-64 butterfly reduce
    #pragma unroll
    for (int off = 32; off > 0; off >>= 1)
        acc += __shfl_down(acc, off, 64);

    __shared__ float wave_sum[BLOCK / 64];
    if ((t & 63) == 0) wave_sum[t >> 6] = acc;
    __syncthreads();

    if (t == 0) {
        float s = wave_sum[0] + wave_sum[1] + wave_sum[2] + wave_sum[3];
        atomicAdd(out, 0.5f * s);
    }
}

extern "C" void kernel_launch(void* const* d_in, const int* in_sizes, int n_in,
                              void* d_out, int out_size, void* d_ws, size_t ws_size,
                              hipStream_t stream)
{
    const float* X   = (const float*)d_in[0];
    const int*   ids = (const int*)  d_in[1];
    const float* C   = (const float*)d_in[2];
    float*       out = (float*)d_out;

    const int B = in_sizes[1];  // 65536 rows

    // d_out is poisoned (0xAA) before timing and not re-zeroed between replays.
    hipMemsetAsync(out, 0, sizeof(float), stream);

    const int grid = (B + ROWS_PER_BLOCK - 1) / ROWS_PER_BLOCK;  // 2048
    cluster_loss_kernel<<<grid, BLOCK, 0, stream>>>(X, ids, C, out, B);
}

// Round 5
// 52.096 us; speedup vs baseline: 1.7261x; 1.1613x over previous
//
#include <hip/hip_runtime.h>

// ClusterLoss: loss = 0.5 * sum_{b,d} (X[b,d] - C[id[b],d])^2
// B=65536, D=1024, K=256.
// Memory-bound: one streaming pass over X (256 MiB); C (1 MiB) is L2-resident.
// X loaded nontemporally (evict-first) so the stream doesn't displace C in L2.
// No memset/atomics: per-block partials -> d_ws (all slots written every call),
// tiny second kernel reduces partials and writes the scalar output.

typedef float f4 __attribute__((ext_vector_type(4)));

#define D_DIM 1024
#define BLOCK 256          // thread t covers float4 at column t*4 -> one row per row-step
#define ROWS_PER_BLOCK 32
#define CHUNK 8            // rows of X batched in flight

__global__ void cluster_loss_main(
    const float* __restrict__ X,
    const int*   __restrict__ ids,
    const float* __restrict__ C,
    float*       __restrict__ partials,
    int B)
{
    const int t = threadIdx.x;
    const int row0 = blockIdx.x * ROWS_PER_BLOCK;
    float acc0 = 0.0f, acc1 = 0.0f;

    if (row0 + ROWS_PER_BLOCK <= B) {
        const float* xb = X + (size_t)row0 * D_DIM + t * 4;
        const float* cb = C + t * 4;

        #pragma unroll 1
        for (int i = 0; i < ROWS_PER_BLOCK; i += CHUNK) {
            int id[CHUNK];
            f4  x[CHUNK];
            // batch-issue ids (uniform -> scalar) + 8 streaming X loads
            #pragma unroll
            for (int u = 0; u < CHUNK; ++u) {
                id[u] = ids[row0 + i + u];
                x[u]  = __builtin_nontemporal_load(
                          reinterpret_cast<const f4*>(xb + (size_t)(i + u) * D_DIM));
            }
            // consume: C gathers (L2-resident) in sub-batches of 4
            #pragma unroll
            for (int h = 0; h < 2; ++h) {
                f4 c[4];
                #pragma unroll
                for (int v = 0; v < 4; ++v)
                    c[v] = *reinterpret_cast<const f4*>(
                             cb + (size_t)id[h * 4 + v] * D_DIM);
                #pragma unroll
                for (int v = 0; v < 4; ++v) {
                    const f4 d = x[h * 4 + v] - c[v];
                    acc0 = fmaf(d.x, d.x, acc0);
                    acc1 = fmaf(d.y, d.y, acc1);
                    acc0 = fmaf(d.z, d.z, acc0);
                    acc1 = fmaf(d.w, d.w, acc1);
                }
            }
        }
    } else {
        for (int row = row0; row < B; ++row) {
            const int id = ids[row];
            const f4 x = __builtin_nontemporal_load(
                           reinterpret_cast<const f4*>(X + (size_t)row * D_DIM + t * 4));
            const f4 c = *reinterpret_cast<const f4*>(C + (size_t)id * D_DIM + t * 4);
            const f4 d = x - c;
            acc0 = fmaf(d.x, d.x, acc0);
            acc1 = fmaf(d.y, d.y, acc1);
            acc0 = fmaf(d.z, d.z, acc0);
            acc1 = fmaf(d.w, d.w, acc1);
        }
    }

    float acc = acc0 + acc1;

    // wave-64 butterfly reduce
    #pragma unroll
    for (int off = 32; off > 0; off >>= 1)
        acc += __shfl_down(acc, off, 64);

    __shared__ float wave_sum[BLOCK / 64];
    if ((t & 63) == 0) wave_sum[t >> 6] = acc;
    __syncthreads();

    if (t == 0)
        partials[blockIdx.x] = wave_sum[0] + wave_sum[1] + wave_sum[2] + wave_sum[3];
}

__global__ __launch_bounds__(256) void cluster_loss_reduce(
    const float* __restrict__ partials,
    float*       __restrict__ out,
    int n)
{
    const int t = threadIdx.x;
    float s = 0.0f;
    for (int i = t; i < n; i += 256) s += partials[i];

    #pragma unroll
    for (int off = 32; off > 0; off >>= 1)
        s += __shfl_down(s, off, 64);

    __shared__ float wave_sum[4];
    if ((t & 63) == 0) wave_sum[t >> 6] = s;
    __syncthreads();

    if (t == 0)
        out[0] = 0.5f * (wave_sum[0] + wave_sum[1] + wave_sum[2] + wave_sum[3]);
}

extern "C" void kernel_launch(void* const* d_in, const int* in_sizes, int n_in,
                              void* d_out, int out_size, void* d_ws, size_t ws_size,
                              hipStream_t stream)
{
    const float* X   = (const float*)d_in[0];
    const int*   ids = (const int*)  d_in[1];
    const float* C   = (const float*)d_in[2];
    float*       out = (float*)d_out;
    float*       partials = (float*)d_ws;   // 2048 floats, all written every call

    const int B = in_sizes[1];  // 65536 rows
    const int grid = (B + ROWS_PER_BLOCK - 1) / ROWS_PER_BLOCK;  // 2048

    cluster_loss_main<<<grid, BLOCK, 0, stream>>>(X, ids, C, partials, B);
    cluster_loss_reduce<<<1, 256, 0, stream>>>(partials, out, grid);
}

// Round 6
// 50.435 us; speedup vs baseline: 1.7830x; 1.0329x over previous
//
#include <hip/hip_runtime.h>

// ClusterLoss: loss = 0.5 * sum_{b,d} (X[b,d] - C[id[b],d])^2
// B=65536, D=1024, K=256.
// Memory-bound: one streaming pass over X (256 MiB); C (1 MiB) is L2-resident.
// X loaded nontemporally (evict-first) so the stream doesn't displace C in L2.
// Grid sized to exact residency (occupancy query) + grid-stride over 8-row
// chunks -> no occupancy tail regardless of the final VGPR count.
// No memset/atomics: per-block partials -> d_ws, tiny reduce kernel finishes.

typedef float f4 __attribute__((ext_vector_type(4)));

#define D_DIM 1024
#define BLOCK 256   // thread t covers float4 at column t*4 -> one row per row-step
#define CHUNK 8     // rows of X batched in flight per grid-stride step
#define MAX_PARTIALS 4096

__global__ void cluster_loss_main(
    const float* __restrict__ X,
    const int*   __restrict__ ids,
    const float* __restrict__ C,
    float*       __restrict__ partials,
    int B)
{
    const int t = threadIdx.x;
    const float* cb = C + t * 4;
    float acc0 = 0.0f, acc1 = 0.0f;

    const int nchunks = B / CHUNK;          // 8192 (B divisible by CHUNK here)

    #pragma unroll 1
    for (int chunk = blockIdx.x; chunk < nchunks; chunk += gridDim.x) {
        const int row0 = chunk * CHUNK;
        const float* xb = X + (size_t)row0 * D_DIM + t * 4;

        int id[CHUNK];
        f4  x[CHUNK];
        // batch-issue ids (uniform -> scalar) + 8 streaming X loads
        #pragma unroll
        for (int u = 0; u < CHUNK; ++u) {
            id[u] = ids[row0 + u];
            x[u]  = __builtin_nontemporal_load(
                      reinterpret_cast<const f4*>(xb + (size_t)u * D_DIM));
        }
        // consume: C gathers (L2-resident) in sub-batches of 4
        #pragma unroll
        for (int h = 0; h < 2; ++h) {
            f4 c[4];
            #pragma unroll
            for (int v = 0; v < 4; ++v)
                c[v] = *reinterpret_cast<const f4*>(
                         cb + (size_t)id[h * 4 + v] * D_DIM);
            #pragma unroll
            for (int v = 0; v < 4; ++v) {
                const f4 d = x[h * 4 + v] - c[v];
                acc0 = fmaf(d.x, d.x, acc0);
                acc1 = fmaf(d.y, d.y, acc1);
                acc0 = fmaf(d.z, d.z, acc0);
                acc1 = fmaf(d.w, d.w, acc1);
            }
        }
    }

    // leftover rows if B % CHUNK != 0 (not hit for B=65536)
    for (int row = nchunks * CHUNK + blockIdx.x; row < B; row += gridDim.x) {
        const int id = ids[row];
        const f4 xv = __builtin_nontemporal_load(
                        reinterpret_cast<const f4*>(X + (size_t)row * D_DIM + t * 4));
        const f4 cv = *reinterpret_cast<const f4*>(cb + (size_t)id * D_DIM);
        const f4 d = xv - cv;
        acc0 = fmaf(d.x, d.x, acc0);
        acc1 = fmaf(d.y, d.y, acc1);
        acc0 = fmaf(d.z, d.z, acc0);
        acc1 = fmaf(d.w, d.w, acc1);
    }

    float acc = acc0 + acc1;

    // wave-64 butterfly reduce
    #pragma unroll
    for (int off = 32; off > 0; off >>= 1)
        acc += __shfl_down(acc, off, 64);

    __shared__ float wave_sum[BLOCK / 64];
    if ((t & 63) == 0) wave_sum[t >> 6] = acc;
    __syncthreads();

    if (t == 0)
        partials[blockIdx.x] = wave_sum[0] + wave_sum[1] + wave_sum[2] + wave_sum[3];
}

__global__ __launch_bounds__(256) void cluster_loss_reduce(
    const float* __restrict__ partials,
    float*       __restrict__ out,
    int n)
{
    const int t = threadIdx.x;
    float s = 0.0f;
    for (int i = t; i < n; i += 256) s += partials[i];

    #pragma unroll
    for (int off = 32; off > 0; off >>= 1)
        s += __shfl_down(s, off, 64);

    __shared__ float wave_sum[4];
    if ((t & 63) == 0) wave_sum[t >> 6] = s;
    __syncthreads();

    if (t == 0)
        out[0] = 0.5f * (wave_sum[0] + wave_sum[1] + wave_sum[2] + wave_sum[3]);
}

extern "C" void kernel_launch(void* const* d_in, const int* in_sizes, int n_in,
                              void* d_out, int out_size, void* d_ws, size_t ws_size,
                              hipStream_t stream)
{
    const float* X   = (const float*)d_in[0];
    const int*   ids = (const int*)  d_in[1];
    const float* C   = (const float*)d_in[2];
    float*       out = (float*)d_out;
    float*       partials = (float*)d_ws;

    const int B = in_sizes[1];  // 65536 rows

    // Size the grid to exact residency so there is no partial last dispatch
    // wave (occupancy tail). Host-side queries only — graph-capture safe.
    int blocksPerCU = 0;
    if (hipOccupancyMaxActiveBlocksPerMultiprocessor(
            &blocksPerCU, cluster_loss_main, BLOCK, 0) != hipSuccess ||
        blocksPerCU <= 0)
        blocksPerCU = 8;

    int numCU = 0;
    if (hipDeviceGetAttribute(&numCU, hipDeviceAttributeMultiprocessorCount, 0)
            != hipSuccess || numCU <= 0)
        numCU = 256;

    int grid = blocksPerCU * numCU;
    const int nchunks = B / CHUNK;
    if (grid > nchunks) grid = nchunks;
    if (grid > MAX_PARTIALS) grid = MAX_PARTIALS;

    cluster_loss_main<<<grid, BLOCK, 0, stream>>>(X, ids, C, partials, B);
    cluster_loss_reduce<<<1, 256, 0, stream>>>(partials, out, grid);
}

// Round 7
// 50.368 us; speedup vs baseline: 1.7854x; 1.0013x over previous
//
#include <hip/hip_runtime.h>

// ClusterLoss: loss = 0.5 * sum_{b,d} (X[b,d] - C[id[b],d])^2
// B=65536, D=1024, K=256.
// Memory-bound: one streaming pass over X (256 MiB); C (1 MiB) is L2-resident.
// X loaded nontemporally (evict-first) so the stream doesn't displace C in L2.
// Grid sized to exact residency (occupancy query) + grid-stride over 8-row
// chunks -> no occupancy tail. Partials -> d_ws; slim vectorized reduce tail.

typedef float f4 __attribute__((ext_vector_type(4)));

#define D_DIM 1024
#define BLOCK 256   // thread t covers float4 at column t*4 -> one row per row-step
#define CHUNK 8     // rows of X batched in flight per grid-stride step
#define MAX_PARTIALS 4096
#define RBLOCK 512  // reduce-kernel threads

__global__ void cluster_loss_main(
    const float* __restrict__ X,
    const int*   __restrict__ ids,
    const float* __restrict__ C,
    float*       __restrict__ partials,
    int B)
{
    const int t = threadIdx.x;
    const float* cb = C + t * 4;
    float acc0 = 0.0f, acc1 = 0.0f;

    const int nchunks = B / CHUNK;          // 8192 (B divisible by CHUNK here)

    #pragma unroll 1
    for (int chunk = blockIdx.x; chunk < nchunks; chunk += gridDim.x) {
        const int row0 = chunk * CHUNK;
        const float* xb = X + (size_t)row0 * D_DIM + t * 4;

        int id[CHUNK];
        f4  x[CHUNK];
        // batch-issue ids (uniform -> scalar) + 8 streaming X loads
        #pragma unroll
        for (int u = 0; u < CHUNK; ++u) {
            id[u] = ids[row0 + u];
            x[u]  = __builtin_nontemporal_load(
                      reinterpret_cast<const f4*>(xb + (size_t)u * D_DIM));
        }
        // consume: C gathers (L2-resident) in sub-batches of 4
        #pragma unroll
        for (int h = 0; h < 2; ++h) {
            f4 c[4];
            #pragma unroll
            for (int v = 0; v < 4; ++v)
                c[v] = *reinterpret_cast<const f4*>(
                         cb + (size_t)id[h * 4 + v] * D_DIM);
            #pragma unroll
            for (int v = 0; v < 4; ++v) {
                const f4 d = x[h * 4 + v] - c[v];
                acc0 = fmaf(d.x, d.x, acc0);
                acc1 = fmaf(d.y, d.y, acc1);
                acc0 = fmaf(d.z, d.z, acc0);
                acc1 = fmaf(d.w, d.w, acc1);
            }
        }
    }

    // leftover rows if B % CHUNK != 0 (not hit for B=65536)
    for (int row = nchunks * CHUNK + blockIdx.x; row < B; row += gridDim.x) {
        const int id = ids[row];
        const f4 xv = __builtin_nontemporal_load(
                        reinterpret_cast<const f4*>(X + (size_t)row * D_DIM + t * 4));
        const f4 cv = *reinterpret_cast<const f4*>(cb + (size_t)id * D_DIM);
        const f4 d = xv - cv;
        acc0 = fmaf(d.x, d.x, acc0);
        acc1 = fmaf(d.y, d.y, acc1);
        acc0 = fmaf(d.z, d.z, acc0);
        acc1 = fmaf(d.w, d.w, acc1);
    }

    float acc = acc0 + acc1;

    // wave-64 butterfly reduce
    #pragma unroll
    for (int off = 32; off > 0; off >>= 1)
        acc += __shfl_down(acc, off, 64);

    __shared__ float wave_sum[BLOCK / 64];
    if ((t & 63) == 0) wave_sum[t >> 6] = acc;
    __syncthreads();

    if (t == 0)
        partials[blockIdx.x] = wave_sum[0] + wave_sum[1] + wave_sum[2] + wave_sum[3];
}

__global__ __launch_bounds__(RBLOCK) void cluster_loss_reduce(
    const float* __restrict__ partials,
    float*       __restrict__ out,
    int n)
{
    const int t = threadIdx.x;
    const int n4 = n >> 2;          // n is a multiple of 4 in practice
    float s = 0.0f;

    // vectorized: 2048 partials = 512 float4 -> one f4 per thread
    for (int i = t; i < n4; i += RBLOCK) {
        const f4 v = reinterpret_cast<const f4*>(partials)[i];
        s += (v.x + v.y) + (v.z + v.w);
    }
    // scalar tail if n % 4 != 0
    for (int i = (n4 << 2) + t; i < n; i += RBLOCK) s += partials[i];

    #pragma unroll
    for (int off = 32; off > 0; off >>= 1)
        s += __shfl_down(s, off, 64);

    __shared__ float wave_sum[RBLOCK / 64];
    if ((t & 63) == 0) wave_sum[t >> 6] = s;
    __syncthreads();

    if (t == 0) {
        float tot = 0.0f;
        #pragma unroll
        for (int w = 0; w < RBLOCK / 64; ++w) tot += wave_sum[w];
        out[0] = 0.5f * tot;
    }
}

extern "C" void kernel_launch(void* const* d_in, const int* in_sizes, int n_in,
                              void* d_out, int out_size, void* d_ws, size_t ws_size,
                              hipStream_t stream)
{
    const float* X   = (const float*)d_in[0];
    const int*   ids = (const int*)  d_in[1];
    const float* C   = (const float*)d_in[2];
    float*       out = (float*)d_out;
    float*       partials = (float*)d_ws;

    const int B = in_sizes[1];  // 65536 rows

    // Size the grid to exact residency so there is no partial last dispatch
    // wave (occupancy tail). Host-side queries only — graph-capture safe.
    int blocksPerCU = 0;
    if (hipOccupancyMaxActiveBlocksPerMultiprocessor(
            &blocksPerCU, cluster_loss_main, BLOCK, 0) != hipSuccess ||
        blocksPerCU <= 0)
        blocksPerCU = 8;

    int numCU = 0;
    if (hipDeviceGetAttribute(&numCU, hipDeviceAttributeMultiprocessorCount, 0)
            != hipSuccess || numCU <= 0)
        numCU = 256;

    int grid = blocksPerCU * numCU;
    const int nchunks = B / CHUNK;
    if (grid > nchunks) grid = nchunks;
    if (grid > MAX_PARTIALS) grid = MAX_PARTIALS;

    cluster_loss_main<<<grid, BLOCK, 0, stream>>>(X, ids, C, partials, B);
    cluster_loss_reduce<<<1, RBLOCK, 0, stream>>>(partials, out, grid);
}

// Round 8
// 46.647 us; speedup vs baseline: 1.9278x; 1.0798x over previous
//
#include <hip/hip_runtime.h>

// ClusterLoss: loss = 0.5 * sum_{b,d} (X[b,d] - C[id[b],d])^2
// B=65536, D=1024, K=256.
// Memory-bound: one streaming pass over X (256 MiB); C (1 MiB) is L2-resident.
// Round-8 A/B: identical to round 7 EXCEPT X loads are plain (no nontemporal
// hint). Hypothesis: hot C lines survive LRU anyway, and the nt bit may cost
// stream efficiency on the X read path.
// Grid sized to exact residency (occupancy query) + grid-stride over 8-row
// chunks -> no occupancy tail. Partials -> d_ws; vectorized reduce tail.

typedef float f4 __attribute__((ext_vector_type(4)));

#define D_DIM 1024
#define BLOCK 256   // thread t covers float4 at column t*4 -> one row per row-step
#define CHUNK 8     // rows of X batched in flight per grid-stride step
#define MAX_PARTIALS 4096
#define RBLOCK 512  // reduce-kernel threads

__global__ void cluster_loss_main(
    const float* __restrict__ X,
    const int*   __restrict__ ids,
    const float* __restrict__ C,
    float*       __restrict__ partials,
    int B)
{
    const int t = threadIdx.x;
    const float* cb = C + t * 4;
    float acc0 = 0.0f, acc1 = 0.0f;

    const int nchunks = B / CHUNK;          // 8192 (B divisible by CHUNK here)

    #pragma unroll 1
    for (int chunk = blockIdx.x; chunk < nchunks; chunk += gridDim.x) {
        const int row0 = chunk * CHUNK;
        const float* xb = X + (size_t)row0 * D_DIM + t * 4;

        int id[CHUNK];
        f4  x[CHUNK];
        // batch-issue ids (uniform -> scalar) + 8 streaming X loads (plain)
        #pragma unroll
        for (int u = 0; u < CHUNK; ++u) {
            id[u] = ids[row0 + u];
            x[u]  = *reinterpret_cast<const f4*>(xb + (size_t)u * D_DIM);
        }
        // consume: C gathers (L2-resident) in sub-batches of 4
        #pragma unroll
        for (int h = 0; h < 2; ++h) {
            f4 c[4];
            #pragma unroll
            for (int v = 0; v < 4; ++v)
                c[v] = *reinterpret_cast<const f4*>(
                         cb + (size_t)id[h * 4 + v] * D_DIM);
            #pragma unroll
            for (int v = 0; v < 4; ++v) {
                const f4 d = x[h * 4 + v] - c[v];
                acc0 = fmaf(d.x, d.x, acc0);
                acc1 = fmaf(d.y, d.y, acc1);
                acc0 = fmaf(d.z, d.z, acc0);
                acc1 = fmaf(d.w, d.w, acc1);
            }
        }
    }

    // leftover rows if B % CHUNK != 0 (not hit for B=65536)
    for (int row = nchunks * CHUNK + blockIdx.x; row < B; row += gridDim.x) {
        const int id = ids[row];
        const f4 xv = *reinterpret_cast<const f4*>(X + (size_t)row * D_DIM + t * 4);
        const f4 cv = *reinterpret_cast<const f4*>(cb + (size_t)id * D_DIM);
        const f4 d = xv - cv;
        acc0 = fmaf(d.x, d.x, acc0);
        acc1 = fmaf(d.y, d.y, acc1);
        acc0 = fmaf(d.z, d.z, acc0);
        acc1 = fmaf(d.w, d.w, acc1);
    }

    float acc = acc0 + acc1;

    // wave-64 butterfly reduce
    #pragma unroll
    for (int off = 32; off > 0; off >>= 1)
        acc += __shfl_down(acc, off, 64);

    __shared__ float wave_sum[BLOCK / 64];
    if ((t & 63) == 0) wave_sum[t >> 6] = acc;
    __syncthreads();

    if (t == 0)
        partials[blockIdx.x] = wave_sum[0] + wave_sum[1] + wave_sum[2] + wave_sum[3];
}

__global__ __launch_bounds__(RBLOCK) void cluster_loss_reduce(
    const float* __restrict__ partials,
    float*       __restrict__ out,
    int n)
{
    const int t = threadIdx.x;
    const int n4 = n >> 2;          // n is a multiple of 4 in practice
    float s = 0.0f;

    for (int i = t; i < n4; i += RBLOCK) {
        const f4 v = reinterpret_cast<const f4*>(partials)[i];
        s += (v.x + v.y) + (v.z + v.w);
    }
    for (int i = (n4 << 2) + t; i < n; i += RBLOCK) s += partials[i];

    #pragma unroll
    for (int off = 32; off > 0; off >>= 1)
        s += __shfl_down(s, off, 64);

    __shared__ float wave_sum[RBLOCK / 64];
    if ((t & 63) == 0) wave_sum[t >> 6] = s;
    __syncthreads();

    if (t == 0) {
        float tot = 0.0f;
        #pragma unroll
        for (int w = 0; w < RBLOCK / 64; ++w) tot += wave_sum[w];
        out[0] = 0.5f * tot;
    }
}

extern "C" void kernel_launch(void* const* d_in, const int* in_sizes, int n_in,
                              void* d_out, int out_size, void* d_ws, size_t ws_size,
                              hipStream_t stream)
{
    const float* X   = (const float*)d_in[0];
    const int*   ids = (const int*)  d_in[1];
    const float* C   = (const float*)d_in[2];
    float*       out = (float*)d_out;
    float*       partials = (float*)d_ws;

    const int B = in_sizes[1];  // 65536 rows

    // Size the grid to exact residency so there is no partial last dispatch
    // wave (occupancy tail). Host-side queries only — graph-capture safe.
    int blocksPerCU = 0;
    if (hipOccupancyMaxActiveBlocksPerMultiprocessor(
            &blocksPerCU, cluster_loss_main, BLOCK, 0) != hipSuccess ||
        blocksPerCU <= 0)
        blocksPerCU = 8;

    int numCU = 0;
    if (hipDeviceGetAttribute(&numCU, hipDeviceAttributeMultiprocessorCount, 0)
            != hipSuccess || numCU <= 0)
        numCU = 256;

    int grid = blocksPerCU * numCU;
    const int nchunks = B / CHUNK;
    if (grid > nchunks) grid = nchunks;
    if (grid > MAX_PARTIALS) grid = MAX_PARTIALS;

    cluster_loss_main<<<grid, BLOCK, 0, stream>>>(X, ids, C, partials, B);
    cluster_loss_reduce<<<1, RBLOCK, 0, stream>>>(partials, out, grid);
}